// Round 8
// baseline (608.879 us; speedup 1.0000x reference)
//
#include <hip/hip_runtime.h>

#define BN_EPS 1e-5f

typedef _Float16 half_t;
typedef _Float16 half2_t __attribute__((ext_vector_type(2)));

#define NBK_MAX 512   // max dst-buckets (256 dsts each) -> n <= 131072
#define EPB 4096      // edges staged per block in bucket kernels

// ---------------- bucketed CSR build ----------------

// K1: count edges per 256-dst bucket (LDS histogram, flush once per block)
__global__ void __launch_bounds__(256) bucket_count_kernel(
    const int* __restrict__ ei, int* __restrict__ bcnt, int E, int etot, int nbk) {
  __shared__ int lh[NBK_MAX];
  for (int i = threadIdx.x; i < nbk; i += 256) lh[i] = 0;
  __syncthreads();
  int base = blockIdx.x * EPB;
  int cnt = min(EPB, etot - base);
  for (int i = threadIdx.x; i < cnt; i += 256) {
    int e = base + i;
    int d = (e < E) ? ei[E + e] : (e - E);
    atomicAdd(&lh[d >> 8], 1);
  }
  __syncthreads();
  for (int i = threadIdx.x; i < nbk; i += 256)
    if (lh[i]) atomicAdd(&bcnt[i], lh[i]);
}

// K2: single-block exclusive scan of bucket counts -> boff (and working copy bcur)
__global__ void __launch_bounds__(512) scan_buckets_kernel(
    const int* __restrict__ bcnt, int* __restrict__ boff, int* __restrict__ bcur,
    int nbk, int etot) {
  __shared__ int wsum[8];
  int tid = threadIdx.x, lane = tid & 63, wid = tid >> 6;
  int v = (tid < nbk) ? bcnt[tid] : 0;
  int incl = v;
#pragma unroll
  for (int off = 1; off < 64; off <<= 1) {
    int t = __shfl_up(incl, off, 64);
    if (lane >= off) incl += t;
  }
  if (lane == 63) wsum[wid] = incl;
  __syncthreads();
  if (wid == 0 && lane < 8) {
    int s = wsum[lane];
#pragma unroll
    for (int off = 1; off < 8; off <<= 1) {
      int t = __shfl_up(s, off, 8);
      if (lane >= off) s += t;
    }
    wsum[lane] = s;
  }
  __syncthreads();
  int woff = (wid > 0) ? wsum[wid - 1] : 0;
  int ex = incl + woff - v;
  if (tid < nbk) { boff[tid] = ex; bcur[tid] = ex; }
  if (tid == 0) boff[nbk] = etot;
}

// K3: scatter (src,dst) pairs into bucket-contiguous staging
__global__ void __launch_bounds__(256) bucket_scatter_kernel(
    const int* __restrict__ ei, int* __restrict__ bcur, int2* __restrict__ bstage,
    int E, int etot, int nbk) {
  __shared__ int2 se[EPB];
  __shared__ int lh[NBK_MAX], lbase[NBK_MAX];
  int base = blockIdx.x * EPB;
  int cnt = min(EPB, etot - base);
  for (int i = threadIdx.x; i < nbk; i += 256) lh[i] = 0;
  __syncthreads();
  for (int i = threadIdx.x; i < cnt; i += 256) {
    int e = base + i;
    int s, d;
    if (e < E) { s = ei[e]; d = ei[E + e]; } else { s = e - E; d = s; }
    se[i] = make_int2(s, d);
    atomicAdd(&lh[d >> 8], 1);
  }
  __syncthreads();
  for (int i = threadIdx.x; i < nbk; i += 256) {
    int c = lh[i];
    lbase[i] = c ? atomicAdd(&bcur[i], c) : 0;
    lh[i] = 0;  // becomes local run cursor
  }
  __syncthreads();
  for (int i = threadIdx.x; i < cnt; i += 256) {
    int2 sd = se[i];
    int b = sd.y >> 8;
    int r = atomicAdd(&lh[b], 1);
    bstage[lbase[b] + r] = sd;
  }
}

// K4: per-bucket degree count + in-bucket scan -> indptr directly (bucket == scan block),
//     plus degree histogram (inverted bucket: 0 = heaviest) for the descending sort.
__global__ void __launch_bounds__(256) deg_indptr_kernel(
    const int2* __restrict__ bstage, const int* __restrict__ boff,
    int* __restrict__ deg, int* __restrict__ indptr, int* __restrict__ dhist, int n) {
  __shared__ int ld[256];
  __shared__ int lh[64];
  __shared__ int wsum[4];
  int b = blockIdx.x, tid = threadIdx.x;
  int d0 = b << 8;
  ld[tid] = 0;
  if (tid < 64) lh[tid] = 0;
  __syncthreads();
  int p0 = boff[b], p1 = boff[b + 1];
  for (int p = p0 + tid; p < p1; p += 256)
    atomicAdd(&ld[bstage[p].y - d0], 1);
  __syncthreads();
  int i = d0 + tid;
  int v = ld[tid];
  if (i < n) {
    deg[i] = v;
    atomicAdd(&lh[63 - min(v, 63)], 1);
  }
  // in-block scan of 256 degrees
  int lane = tid & 63, wid = tid >> 6;
  int incl = v;
#pragma unroll
  for (int off = 1; off < 64; off <<= 1) {
    int t = __shfl_up(incl, off, 64);
    if (lane >= off) incl += t;
  }
  if (lane == 63) wsum[wid] = incl;
  __syncthreads();
  if (tid == 0) {
    int s = 0;
#pragma unroll
    for (int w = 0; w < 4; w++) { int t = wsum[w]; wsum[w] = s; s += t; }
  }
  __syncthreads();
  incl += wsum[wid];
  if (i < n) indptr[i + 1] = p0 + incl;
  if (b == 0 && tid == 0) indptr[0] = 0;
  __syncthreads();
  if (tid < 64 && lh[tid]) atomicAdd(&dhist[tid], lh[tid]);
}

// K5: exclusive scan of the 64 degree-histogram buckets -> dcur
__global__ void __launch_bounds__(64) scan64_kernel(const int* __restrict__ dhist,
                                                    int* __restrict__ dcur) {
  int lane = threadIdx.x;
  int v = dhist[lane];
  int incl = v;
#pragma unroll
  for (int off = 1; off < 64; off <<= 1) {
    int t = __shfl_up(incl, off, 64);
    if (lane >= off) incl += t;
  }
  dcur[lane] = incl - v;  // exclusive
}

// K6: build degree-descending permutation (counting sort, LDS-batched reservations)
__global__ void __launch_bounds__(256) perm_kernel(const int* __restrict__ deg,
                                                   int* __restrict__ dcur,
                                                   int* __restrict__ perm, int n) {
  __shared__ int lh[64], lbase[64];
  if (threadIdx.x < 64) lh[threadIdx.x] = 0;
  __syncthreads();
  int i = blockIdx.x * blockDim.x + threadIdx.x;
  int bk = 0, lr = 0;
  if (i < n) {
    bk = 63 - min(deg[i], 63);
    lr = atomicAdd(&lh[bk], 1);
  }
  __syncthreads();
  if (threadIdx.x < 64 && lh[threadIdx.x])
    lbase[threadIdx.x] = atomicAdd(&dcur[threadIdx.x], lh[threadIdx.x]);
  __syncthreads();
  if (i < n) perm[lbase[bk] + lr] = i;
}

// K7: fine placement within each bucket (LDS cursors; writes confined to ~17KB window)
__global__ void __launch_bounds__(256) fine_place_kernel(
    const int2* __restrict__ bstage, const int* __restrict__ boff,
    const int* __restrict__ indptr, int* __restrict__ csrc, int n) {
  __shared__ int cur[256];
  int b = blockIdx.x;
  int d0 = b << 8;
  int i = d0 + threadIdx.x;
  cur[threadIdx.x] = (i < n) ? indptr[i] : 0;
  __syncthreads();
  int p0 = boff[b], p1 = boff[b + 1];
  for (int p = p0 + threadIdx.x; p < p1; p += 256) {
    int2 sd = bstage[p];
    int pos = atomicAdd(&cur[sd.y - d0], 1);
    csrc[pos] = sd.x;
  }
}

// ---------------- node transform ----------------
// Each thread computes JT consecutive outputs j for one node.
// xl (fp16, padded [n][H][CPAD]) = x@Wl+bl ; xr (fp32, [n][HC]) = x@Wr+br

template <int CIN, int H, int C, int CPAD, int JT>
__global__ void __launch_bounds__(256) transform_kernel(
    const float* __restrict__ x, const float* __restrict__ Wl, const float* __restrict__ Wr,
    const float* __restrict__ bl, const float* __restrict__ br, half_t* __restrict__ xl,
    float* __restrict__ xr, int n) {
  constexpr int HC = H * C;
  constexpr int TPN = HC / JT;  // threads per node
  __shared__ float sW[2 * CIN * HC];
  for (int i = threadIdx.x; i < CIN * HC; i += blockDim.x) {
    sW[i] = Wl[i];
    sW[CIN * HC + i] = Wr[i];
  }
  __syncthreads();
  int idx = blockIdx.x * blockDim.x + threadIdx.x;
  if (idx >= n * TPN) return;
  int node = idx / TPN;
  int j0 = (idx - node * TPN) * JT;

  float al[JT], ar[JT];
#pragma unroll
  for (int jj = 0; jj < JT; jj++) {
    al[jj] = bl[j0 + jj];
    ar[jj] = br[j0 + jj];
  }
  const float2* xrow = reinterpret_cast<const float2*>(x + (size_t)node * CIN);
#pragma unroll
  for (int k2 = 0; k2 < CIN / 2; k2++) {
    float2 xv = xrow[k2];
#pragma unroll
    for (int q = 0; q < 2; q++) {
      float xs = q ? xv.y : xv.x;
      int k = 2 * k2 + q;
#pragma unroll
      for (int jj = 0; jj < JT; jj++) {
        al[jj] = fmaf(xs, sW[k * HC + j0 + jj], al[jj]);
        ar[jj] = fmaf(xs, sW[CIN * HC + k * HC + j0 + jj], ar[jj]);
      }
    }
  }
#pragma unroll
  for (int jj = 0; jj < JT; jj++) {
    int j = j0 + jj;
    int h = j / C, c = j - h * C;
    xl[((size_t)node * H + h) * CPAD + c] = (half_t)al[jj];
    xr[(size_t)node * HC + j] = ar[jj];
  }
}

// ---------------- fused edge pass ----------------
// Thread t -> slot = t/H (degree-descending order), node = perm[slot], head = t%H.
// Waves thus have uniform degree; heavy blocks launch first (LPT packing).
// CSR gather of padded fp16 rows via uint4; 3-deep pipeline + 3-ahead index queue.
// MODE 0: +bias,BN  1: +bias,BN,ELU  2: raw

#define IDX(K) csrc[p0 + (((K) < cnt) ? (K) : cnt - 1)]

#define ROW(B, IR)                                                                \
  {                                                                               \
    const uint4* xp_ = reinterpret_cast<const uint4*>(xlh + (size_t)(IR) * HCP);  \
    _Pragma("unroll") for (int i_ = 0; i_ < NB; i_++) B[i_] = xp_[i_];            \
  }

#define COMP_ROW(B, M)                                                                      \
  {                                                                                         \
    const half2_t* hp_ = reinterpret_cast<const half2_t*>(B);                               \
    float xs_[C];                                                                           \
    _Pragma("unroll") for (int i = 0; i < C / 2; i++) {                                     \
      xs_[2 * i] = (float)hp_[i].x;                                                         \
      xs_[2 * i + 1] = (float)hp_[i].y;                                                     \
    }                                                                                       \
    float e_ = 0.f;                                                                         \
    _Pragma("unroll") for (int c = 0; c < C; c++) {                                         \
      float m_ = xs_[c] + xr_reg[c];                                                        \
      m_ = (m_ > 0.f) ? m_ : 0.2f * m_;                                                     \
      e_ = fmaf(att_reg[c], m_, e_);                                                        \
    }                                                                                       \
    float ex_ = ((M) < cnt) ? __expf(e_) : 0.f;                                             \
    den += ex_;                                                                             \
    _Pragma("unroll") for (int c = 0; c < C; c++) acc[c] = fmaf(ex_, xs_[c], acc[c]);       \
  }

template <int H, int C, int CPAD, int MODE>
__global__ void __launch_bounds__(256) edge_kernel(
    const half_t* __restrict__ xl, const float* __restrict__ xr,
    const int* __restrict__ indptr, const int* __restrict__ csrc,
    const int* __restrict__ perm, const float* __restrict__ att,
    const float* __restrict__ bias, const float* __restrict__ g,
    const float* __restrict__ be, const float* __restrict__ rm,
    const float* __restrict__ rv, float* __restrict__ out, int n) {
  constexpr int HC = H * C;
  constexpr int HCP = H * CPAD;
  constexpr int NB = CPAD / 8;  // uint4 loads per row
  int t = blockIdx.x * blockDim.x + threadIdx.x;
  if (t >= n * H) return;
  int slot = t / H;
  int h = t - slot * H;
  int node = perm[slot];

  float xr_reg[C], att_reg[C];
  const float2* xrp = reinterpret_cast<const float2*>(xr + (size_t)node * HC + h * C);
#pragma unroll
  for (int i = 0; i < C / 2; i++) {
    float2 v = xrp[i];
    xr_reg[2 * i] = v.x;
    xr_reg[2 * i + 1] = v.y;
  }
#pragma unroll
  for (int c = 0; c < C; c++) att_reg[c] = att[h * C + c];

  float acc[C];
#pragma unroll
  for (int c = 0; c < C; c++) acc[c] = 0.f;
  float den = 0.f;

  int p0 = indptr[node], p1 = indptr[node + 1];
  int cnt = p1 - p0;
  const half_t* xlh = xl + h * CPAD;

  uint4 B0[NB], B1[NB], B2[NB];
  int i0, i1, i2;
  i0 = IDX(0); i1 = IDX(1); i2 = IDX(2);
  ROW(B0, i0) ROW(B1, i1) ROW(B2, i2)
  i0 = IDX(3); i1 = IDX(4); i2 = IDX(5);
  int cnt3 = ((cnt + 2) / 3) * 3;
  for (int m = 0; m < cnt3; m += 3) {
    COMP_ROW(B0, m)     ROW(B0, i0) i0 = IDX(m + 6);
    COMP_ROW(B1, m + 1) ROW(B1, i1) i1 = IDX(m + 7);
    COMP_ROW(B2, m + 2) ROW(B2, i2) i2 = IDX(m + 8);
  }

  float inv = 1.f / den;
  float2* orow = reinterpret_cast<float2*>(out + (size_t)node * HC + h * C);
#pragma unroll
  for (int c2 = 0; c2 < C / 2; c2++) {
    float2 ov;
#pragma unroll
    for (int q = 0; q < 2; q++) {
      int c = 2 * c2 + q;
      float val = acc[c] * inv;
      if constexpr (MODE != 2) {
        int j = h * C + c;
        val += bias[j];
        float sc = g[j] * rsqrtf(rv[j] + BN_EPS);
        val = fmaf(sc, val - rm[j], be[j]);
        if constexpr (MODE == 1) val = (val > 0.f) ? val : expm1f(val);
      }
      if (q) ov.y = val; else ov.x = val;
    }
    orow[c2] = ov;
  }
}

// ---------------- layer-4 tail: mean over heads + bias + BN + mu/logvar heads ----------------

__global__ void final_kernel(const float* __restrict__ r4, const float* __restrict__ b4,
                             const float* __restrict__ g4, const float* __restrict__ be4,
                             const float* __restrict__ rm4, const float* __restrict__ rv4,
                             const float* __restrict__ Wmu, const float* __restrict__ bmu,
                             const float* __restrict__ Wlv, const float* __restrict__ blv,
                             float* __restrict__ out, int n) {
  int node = blockIdx.x * blockDim.x + threadIdx.x;
  if (node >= n) return;
  float hsum[10];
#pragma unroll
  for (int c = 0; c < 10; c++) hsum[c] = 0.f;
  const float* r = r4 + (size_t)node * 50;
#pragma unroll
  for (int h = 0; h < 5; h++)
#pragma unroll
    for (int c = 0; c < 10; c++) hsum[c] += r[h * 10 + c];
  float hv[10];
#pragma unroll
  for (int c = 0; c < 10; c++) {
    float v = hsum[c] * 0.2f + b4[c];
    float sc = g4[c] * rsqrtf(rv4[c] + BN_EPS);
    hv[c] = fmaf(sc, v - rm4[c], be4[c]);
  }
#pragma unroll
  for (int j = 0; j < 10; j++) {
    float mu = bmu[j], lv = blv[j];
#pragma unroll
    for (int c = 0; c < 10; c++) {
      mu = fmaf(hv[c], Wmu[c * 10 + j], mu);
      lv = fmaf(hv[c], Wlv[c * 10 + j], lv);
    }
    out[(size_t)node * 10 + j] = mu;
    out[(size_t)n * 10 + (size_t)node * 10 + j] = lv;
  }
}

// ---------------- launch ----------------

extern "C" void kernel_launch(void* const* d_in, const int* in_sizes, int n_in,
                              void* d_out, int out_size, void* d_ws, size_t ws_size,
                              hipStream_t stream) {
  const float* x = (const float*)d_in[0];
  const int* ei = (const int*)d_in[1];
  const int n = in_sizes[0] / 22;
  const int E = in_sizes[1] / 2;
  const int etot = E + n;
  const int nbk = (n + 255) >> 8;  // 256-dst buckets

  auto P = [&](int i) { return (const float*)d_in[i]; };

  char* ws = (char*)d_ws;
  size_t off = 0;
  auto alloc = [&](size_t bytes) -> void* {
    void* p = ws + off;
    off += (bytes + 255) & ~(size_t)255;
    return p;
  };
  half_t* xl = (half_t*)alloc((size_t)n * 80 * 2);  // max H*CPAD = 5*16 = 80 halves
  float* xr = (float*)alloc((size_t)n * 54 * 4);
  float* hb = (float*)alloc((size_t)n * 54 * 4);
  int* deg = (int*)alloc((size_t)n * 4);
  int* indptr = (int*)alloc((size_t)(n + 1) * 4);
  int* csrc = (int*)alloc((size_t)etot * 4);
  int* perm = (int*)alloc((size_t)n * 4);
  // zeroed zone: bcnt(nbk+1) | dhist(64) | dcur(64)
  int* bcnt = (int*)alloc((size_t)(nbk + 129) * 4);
  int* dhist = bcnt + nbk + 1;
  int* dcur = dhist + 64;
  int* boff = (int*)alloc((size_t)(nbk + 1) * 4);
  int* bcur = (int*)alloc((size_t)(nbk + 1) * 4);
  // bstage aliases xl/xr (only live before transforms run; same-stream ordering)
  int2* bstage = (int2*)xl;

  unsigned bb = (unsigned)((etot + EPB - 1) / EPB);
  unsigned nblk = (unsigned)((n + 255) / 256);

  hipMemsetAsync(bcnt, 0, (size_t)(nbk + 129) * 4, stream);
  bucket_count_kernel<<<bb, 256, 0, stream>>>(ei, bcnt, E, etot, nbk);
  scan_buckets_kernel<<<1, 512, 0, stream>>>(bcnt, boff, bcur, nbk, etot);
  bucket_scatter_kernel<<<bb, 256, 0, stream>>>(ei, bcur, bstage, E, etot, nbk);
  deg_indptr_kernel<<<(unsigned)nbk, 256, 0, stream>>>(bstage, boff, deg, indptr, dhist, n);
  scan64_kernel<<<1, 64, 0, stream>>>(dhist, dcur);
  perm_kernel<<<nblk, 256, 0, stream>>>(deg, dcur, perm, n);
  fine_place_kernel<<<(unsigned)nbk, 256, 0, stream>>>(bstage, boff, indptr, csrc, n);

  // layer 1: cin=22, H=3, C=18 (CPAD=24), concat, BN+ELU
  transform_kernel<22, 3, 18, 24, 6><<<(unsigned)(((size_t)n * 9 + 255) / 256), 256, 0, stream>>>(
      x, P(2), P(3), P(4), P(5), xl, xr, n);
  edge_kernel<3, 18, 24, 1><<<(unsigned)(((size_t)n * 3 + 255) / 256), 256, 0, stream>>>(
      xl, xr, indptr, csrc, perm, P(6), P(7), P(8), P(9), P(10), P(11), hb, n);

  // layer 2: cin=54, H=3, C=14 (CPAD=16), concat, BN
  transform_kernel<54, 3, 14, 16, 6><<<(unsigned)(((size_t)n * 7 + 255) / 256), 256, 0, stream>>>(
      hb, P(12), P(13), P(14), P(15), xl, xr, n);
  edge_kernel<3, 14, 16, 0><<<(unsigned)(((size_t)n * 3 + 255) / 256), 256, 0, stream>>>(
      xl, xr, indptr, csrc, perm, P(16), P(17), P(18), P(19), P(20), P(21), hb, n);

  // layer 3: cin=42, H=3, C=12 (CPAD=16), concat, BN
  transform_kernel<42, 3, 12, 16, 6><<<(unsigned)(((size_t)n * 6 + 255) / 256), 256, 0, stream>>>(
      hb, P(22), P(23), P(24), P(25), xl, xr, n);
  edge_kernel<3, 12, 16, 0><<<(unsigned)(((size_t)n * 3 + 255) / 256), 256, 0, stream>>>(
      xl, xr, indptr, csrc, perm, P(26), P(27), P(28), P(29), P(30), P(31), hb, n);

  // layer 4: cin=36, H=5, C=10 (CPAD=16), mean over heads (raw; epilogue in final_kernel)
  transform_kernel<36, 5, 10, 16, 10><<<(unsigned)(((size_t)n * 5 + 255) / 256), 256, 0, stream>>>(
      hb, P(32), P(33), P(34), P(35), xl, xr, n);
  edge_kernel<5, 10, 16, 2><<<(unsigned)(((size_t)n * 5 + 255) / 256), 256, 0, stream>>>(
      xl, xr, indptr, csrc, perm, P(36), nullptr, nullptr, nullptr, nullptr, nullptr, hb, n);

  final_kernel<<<nblk, 256, 0, stream>>>(
      hb, P(37), P(38), P(39), P(40), P(41), P(42), P(43), P(44), P(45), (float*)d_out, n);
}

// Round 9
// 512.815 us; speedup vs baseline: 1.1873x; 1.1873x over previous
//
#include <hip/hip_runtime.h>

#define BN_EPS 1e-5f

typedef _Float16 half_t;
typedef _Float16 half2_t __attribute__((ext_vector_type(2)));

#define NBK_MAX 512   // max dst-buckets (256 dsts each) -> n <= 131072
#define EPB 4096      // edges staged per block in bucket kernels
#define REC 64        // xl record: 64 halves = 128 B, line-aligned

// ---------------- bucketed CSR build ----------------

// K1: count edges per 256-dst bucket (LDS histogram, flush once per block)
__global__ void __launch_bounds__(256) bucket_count_kernel(
    const int* __restrict__ ei, int* __restrict__ bcnt, int E, int etot, int nbk) {
  __shared__ int lh[NBK_MAX];
  for (int i = threadIdx.x; i < nbk; i += 256) lh[i] = 0;
  __syncthreads();
  int base = blockIdx.x * EPB;
  int cnt = min(EPB, etot - base);
  for (int i = threadIdx.x; i < cnt; i += 256) {
    int e = base + i;
    int d = (e < E) ? ei[E + e] : (e - E);
    atomicAdd(&lh[d >> 8], 1);
  }
  __syncthreads();
  for (int i = threadIdx.x; i < nbk; i += 256)
    if (lh[i]) atomicAdd(&bcnt[i], lh[i]);
}

// K2: single-block exclusive scan of bucket counts -> boff (and working copy bcur)
__global__ void __launch_bounds__(512) scan_buckets_kernel(
    const int* __restrict__ bcnt, int* __restrict__ boff, int* __restrict__ bcur,
    int nbk, int etot) {
  __shared__ int wsum[8];
  int tid = threadIdx.x, lane = tid & 63, wid = tid >> 6;
  int v = (tid < nbk) ? bcnt[tid] : 0;
  int incl = v;
#pragma unroll
  for (int off = 1; off < 64; off <<= 1) {
    int t = __shfl_up(incl, off, 64);
    if (lane >= off) incl += t;
  }
  if (lane == 63) wsum[wid] = incl;
  __syncthreads();
  if (wid == 0 && lane < 8) {
    int s = wsum[lane];
#pragma unroll
    for (int off = 1; off < 8; off <<= 1) {
      int t = __shfl_up(s, off, 8);
      if (lane >= off) s += t;
    }
    wsum[lane] = s;
  }
  __syncthreads();
  int woff = (wid > 0) ? wsum[wid - 1] : 0;
  int ex = incl + woff - v;
  if (tid < nbk) { boff[tid] = ex; bcur[tid] = ex; }
  if (tid == 0) boff[nbk] = etot;
}

// K3: scatter (src,dst) pairs into bucket-contiguous staging
__global__ void __launch_bounds__(256) bucket_scatter_kernel(
    const int* __restrict__ ei, int* __restrict__ bcur, int2* __restrict__ bstage,
    int E, int etot, int nbk) {
  __shared__ int2 se[EPB];
  __shared__ int lh[NBK_MAX], lbase[NBK_MAX];
  int base = blockIdx.x * EPB;
  int cnt = min(EPB, etot - base);
  for (int i = threadIdx.x; i < nbk; i += 256) lh[i] = 0;
  __syncthreads();
  for (int i = threadIdx.x; i < cnt; i += 256) {
    int e = base + i;
    int s, d;
    if (e < E) { s = ei[e]; d = ei[E + e]; } else { s = e - E; d = s; }
    se[i] = make_int2(s, d);
    atomicAdd(&lh[d >> 8], 1);
  }
  __syncthreads();
  for (int i = threadIdx.x; i < nbk; i += 256) {
    int c = lh[i];
    lbase[i] = c ? atomicAdd(&bcur[i], c) : 0;
    lh[i] = 0;  // becomes local run cursor
  }
  __syncthreads();
  for (int i = threadIdx.x; i < cnt; i += 256) {
    int2 sd = se[i];
    int b = sd.y >> 8;
    int r = atomicAdd(&lh[b], 1);
    bstage[lbase[b] + r] = sd;
  }
}

// K4: fused per-bucket degree count + in-bucket scan -> indptr, then in-LDS-cursor
//     placement (second bstage pass is L2-hot; csrc writes confined to ~17KB window)
__global__ void __launch_bounds__(256) csr_finalize_kernel(
    const int2* __restrict__ bstage, const int* __restrict__ boff,
    int* __restrict__ indptr, int* __restrict__ csrc, int n) {
  __shared__ int ld[256];
  __shared__ int wsum[4];
  int b = blockIdx.x, tid = threadIdx.x;
  int d0 = b << 8;
  ld[tid] = 0;
  __syncthreads();
  int p0 = boff[b], p1 = boff[b + 1];
  for (int p = p0 + tid; p < p1; p += 256)
    atomicAdd(&ld[bstage[p].y - d0], 1);
  __syncthreads();
  int v = ld[tid];
  // in-block scan of 256 degrees
  int lane = tid & 63, wid = tid >> 6;
  int incl = v;
#pragma unroll
  for (int off = 1; off < 64; off <<= 1) {
    int t = __shfl_up(incl, off, 64);
    if (lane >= off) incl += t;
  }
  if (lane == 63) wsum[wid] = incl;
  __syncthreads();
  if (tid == 0) {
    int s = 0;
#pragma unroll
    for (int w = 0; w < 4; w++) { int t = wsum[w]; wsum[w] = s; s += t; }
  }
  __syncthreads();
  incl += wsum[wid];
  int i = d0 + tid;
  if (i < n) indptr[i + 1] = p0 + incl;
  if (b == 0 && tid == 0) indptr[0] = 0;
  __syncthreads();
  ld[tid] = p0 + incl - v;  // exclusive start -> cursor
  __syncthreads();
  for (int p = p0 + tid; p < p1; p += 256) {
    int2 sd = bstage[p];
    int pos = atomicAdd(&ld[sd.y - d0], 1);
    csrc[pos] = sd.x;
  }
}

// ---------------- node transform ----------------
// Each thread computes JT consecutive outputs j for one node.
// xl (fp16, [n][REC] 128B line-aligned records, head h at half-offset h*C) = x@Wl+bl
// xr (fp32, [n][HC]) = x@Wr+br

template <int CIN, int H, int C, int JT>
__global__ void __launch_bounds__(256) transform_kernel(
    const float* __restrict__ x, const float* __restrict__ Wl, const float* __restrict__ Wr,
    const float* __restrict__ bl, const float* __restrict__ br, half_t* __restrict__ xl,
    float* __restrict__ xr, int n) {
  constexpr int HC = H * C;
  constexpr int TPN = HC / JT;  // threads per node
  __shared__ float sW[2 * CIN * HC];
  for (int i = threadIdx.x; i < CIN * HC; i += blockDim.x) {
    sW[i] = Wl[i];
    sW[CIN * HC + i] = Wr[i];
  }
  __syncthreads();
  int idx = blockIdx.x * blockDim.x + threadIdx.x;
  if (idx >= n * TPN) return;
  int node = idx / TPN;
  int j0 = (idx - node * TPN) * JT;

  float al[JT], ar[JT];
#pragma unroll
  for (int jj = 0; jj < JT; jj++) {
    al[jj] = bl[j0 + jj];
    ar[jj] = br[j0 + jj];
  }
  const float2* xrow = reinterpret_cast<const float2*>(x + (size_t)node * CIN);
#pragma unroll
  for (int k2 = 0; k2 < CIN / 2; k2++) {
    float2 xv = xrow[k2];
#pragma unroll
    for (int q = 0; q < 2; q++) {
      float xs = q ? xv.y : xv.x;
      int k = 2 * k2 + q;
#pragma unroll
      for (int jj = 0; jj < JT; jj++) {
        al[jj] = fmaf(xs, sW[k * HC + j0 + jj], al[jj]);
        ar[jj] = fmaf(xs, sW[CIN * HC + k * HC + j0 + jj], ar[jj]);
      }
    }
  }
#pragma unroll
  for (int jj = 0; jj < JT; jj++) {
    int j = j0 + jj;
    xl[(size_t)node * REC + j] = (half_t)al[jj];   // heads packed: offset h*C+c == j
    xr[(size_t)node * HC + j] = ar[jj];
  }
}

// ---------------- fused edge pass ----------------
// One thread per (node, head). Each gathered node record is ONE 128B line; per-head
// slice read as C/2 dword (half2) loads. 3-deep row pipeline + 3-ahead index queue.
// MODE 0: +bias,BN  1: +bias,BN,ELU  2: raw

#define IDX(K) csrc[p0 + (((K) < cnt) ? (K) : cnt - 1)]

#define ROW(B, IR)                                                                  \
  {                                                                                 \
    const uint* xp_ = reinterpret_cast<const uint*>(xlh + (size_t)(IR) * REC);      \
    _Pragma("unroll") for (int i_ = 0; i_ < C2; i_++) B[i_] = xp_[i_];              \
  }

#define COMP_ROW(B, M)                                                                      \
  {                                                                                         \
    const half2_t* hp_ = reinterpret_cast<const half2_t*>(B);                               \
    float xs_[C];                                                                           \
    _Pragma("unroll") for (int i = 0; i < C2; i++) {                                        \
      xs_[2 * i] = (float)hp_[i].x;                                                         \
      xs_[2 * i + 1] = (float)hp_[i].y;                                                     \
    }                                                                                       \
    float e_ = 0.f;                                                                         \
    _Pragma("unroll") for (int c = 0; c < C; c++) {                                         \
      float m_ = xs_[c] + xr_reg[c];                                                        \
      m_ = (m_ > 0.f) ? m_ : 0.2f * m_;                                                     \
      e_ = fmaf(att_reg[c], m_, e_);                                                        \
    }                                                                                       \
    float ex_ = ((M) < cnt) ? __expf(e_) : 0.f;                                             \
    den += ex_;                                                                             \
    _Pragma("unroll") for (int c = 0; c < C; c++) acc[c] = fmaf(ex_, xs_[c], acc[c]);       \
  }

template <int H, int C, int MODE>
__global__ void __launch_bounds__(256) edge_kernel(
    const half_t* __restrict__ xl, const float* __restrict__ xr,
    const int* __restrict__ indptr, const int* __restrict__ csrc,
    const float* __restrict__ att, const float* __restrict__ bias,
    const float* __restrict__ g, const float* __restrict__ be,
    const float* __restrict__ rm, const float* __restrict__ rv,
    float* __restrict__ out, int n) {
  constexpr int HC = H * C;
  constexpr int C2 = C / 2;
  int t = blockIdx.x * blockDim.x + threadIdx.x;
  if (t >= n * H) return;
  int node = t / H;
  int h = t - node * H;

  float xr_reg[C], att_reg[C];
  const float2* xrp = reinterpret_cast<const float2*>(xr + (size_t)node * HC + h * C);
#pragma unroll
  for (int i = 0; i < C2; i++) {
    float2 v = xrp[i];
    xr_reg[2 * i] = v.x;
    xr_reg[2 * i + 1] = v.y;
  }
#pragma unroll
  for (int c = 0; c < C; c++) att_reg[c] = att[h * C + c];

  float acc[C];
#pragma unroll
  for (int c = 0; c < C; c++) acc[c] = 0.f;
  float den = 0.f;

  int p0 = indptr[node], p1 = indptr[node + 1];
  int cnt = p1 - p0;
  const half_t* xlh = xl + h * C;  // head slice within the 128B record

  uint B0[C2], B1[C2], B2[C2];
  int i0, i1, i2;
  i0 = IDX(0); i1 = IDX(1); i2 = IDX(2);
  ROW(B0, i0) ROW(B1, i1) ROW(B2, i2)
  i0 = IDX(3); i1 = IDX(4); i2 = IDX(5);
  int cnt3 = ((cnt + 2) / 3) * 3;
  for (int m = 0; m < cnt3; m += 3) {
    COMP_ROW(B0, m)     ROW(B0, i0) i0 = IDX(m + 6);
    COMP_ROW(B1, m + 1) ROW(B1, i1) i1 = IDX(m + 7);
    COMP_ROW(B2, m + 2) ROW(B2, i2) i2 = IDX(m + 8);
  }

  float inv = 1.f / den;
  float2* orow = reinterpret_cast<float2*>(out + (size_t)node * HC + h * C);
#pragma unroll
  for (int c2 = 0; c2 < C2; c2++) {
    float2 ov;
#pragma unroll
    for (int q = 0; q < 2; q++) {
      int c = 2 * c2 + q;
      float val = acc[c] * inv;
      if constexpr (MODE != 2) {
        int j = h * C + c;
        val += bias[j];
        float sc = g[j] * rsqrtf(rv[j] + BN_EPS);
        val = fmaf(sc, val - rm[j], be[j]);
        if constexpr (MODE == 1) val = (val > 0.f) ? val : expm1f(val);
      }
      if (q) ov.y = val; else ov.x = val;
    }
    orow[c2] = ov;
  }
}

// ---------------- layer-4 tail: mean over heads + bias + BN + mu/logvar heads ----------------

__global__ void final_kernel(const float* __restrict__ r4, const float* __restrict__ b4,
                             const float* __restrict__ g4, const float* __restrict__ be4,
                             const float* __restrict__ rm4, const float* __restrict__ rv4,
                             const float* __restrict__ Wmu, const float* __restrict__ bmu,
                             const float* __restrict__ Wlv, const float* __restrict__ blv,
                             float* __restrict__ out, int n) {
  int node = blockIdx.x * blockDim.x + threadIdx.x;
  if (node >= n) return;
  float hsum[10];
#pragma unroll
  for (int c = 0; c < 10; c++) hsum[c] = 0.f;
  const float* r = r4 + (size_t)node * 50;
#pragma unroll
  for (int h = 0; h < 5; h++)
#pragma unroll
    for (int c = 0; c < 10; c++) hsum[c] += r[h * 10 + c];
  float hv[10];
#pragma unroll
  for (int c = 0; c < 10; c++) {
    float v = hsum[c] * 0.2f + b4[c];
    float sc = g4[c] * rsqrtf(rv4[c] + BN_EPS);
    hv[c] = fmaf(sc, v - rm4[c], be4[c]);
  }
#pragma unroll
  for (int j = 0; j < 10; j++) {
    float mu = bmu[j], lv = blv[j];
#pragma unroll
    for (int c = 0; c < 10; c++) {
      mu = fmaf(hv[c], Wmu[c * 10 + j], mu);
      lv = fmaf(hv[c], Wlv[c * 10 + j], lv);
    }
    out[(size_t)node * 10 + j] = mu;
    out[(size_t)n * 10 + (size_t)node * 10 + j] = lv;
  }
}

// ---------------- launch ----------------

extern "C" void kernel_launch(void* const* d_in, const int* in_sizes, int n_in,
                              void* d_out, int out_size, void* d_ws, size_t ws_size,
                              hipStream_t stream) {
  const float* x = (const float*)d_in[0];
  const int* ei = (const int*)d_in[1];
  const int n = in_sizes[0] / 22;
  const int E = in_sizes[1] / 2;
  const int etot = E + n;
  const int nbk = (n + 255) >> 8;  // 256-dst buckets

  auto P = [&](int i) { return (const float*)d_in[i]; };

  char* ws = (char*)d_ws;
  size_t off = 0;
  auto alloc = [&](size_t bytes) -> void* {
    void* p = ws + off;
    off += (bytes + 255) & ~(size_t)255;
    return p;
  };
  half_t* xl = (half_t*)alloc((size_t)n * REC * 2);  // 128B-aligned records
  float* xr = (float*)alloc((size_t)n * 54 * 4);
  float* hb = (float*)alloc((size_t)n * 54 * 4);
  int* indptr = (int*)alloc((size_t)(n + 1) * 4);
  int* csrc = (int*)alloc((size_t)etot * 4);
  int* bcnt = (int*)alloc((size_t)(nbk + 1) * 4);
  int* boff = (int*)alloc((size_t)(nbk + 1) * 4);
  int* bcur = (int*)alloc((size_t)(nbk + 1) * 4);
  // bstage aliases xl/xr region (only live before transforms run; same-stream ordering)
  int2* bstage = (int2*)xl;

  unsigned bb = (unsigned)((etot + EPB - 1) / EPB);
  unsigned nblk = (unsigned)((n + 255) / 256);

  hipMemsetAsync(bcnt, 0, (size_t)(nbk + 1) * 4, stream);
  bucket_count_kernel<<<bb, 256, 0, stream>>>(ei, bcnt, E, etot, nbk);
  scan_buckets_kernel<<<1, 512, 0, stream>>>(bcnt, boff, bcur, nbk, etot);
  bucket_scatter_kernel<<<bb, 256, 0, stream>>>(ei, bcur, bstage, E, etot, nbk);
  csr_finalize_kernel<<<(unsigned)nbk, 256, 0, stream>>>(bstage, boff, indptr, csrc, n);

  // layer 1: cin=22, H=3, C=18, concat, BN+ELU
  transform_kernel<22, 3, 18, 6><<<(unsigned)(((size_t)n * 9 + 255) / 256), 256, 0, stream>>>(
      x, P(2), P(3), P(4), P(5), xl, xr, n);
  edge_kernel<3, 18, 1><<<(unsigned)(((size_t)n * 3 + 255) / 256), 256, 0, stream>>>(
      xl, xr, indptr, csrc, P(6), P(7), P(8), P(9), P(10), P(11), hb, n);

  // layer 2: cin=54, H=3, C=14, concat, BN
  transform_kernel<54, 3, 14, 6><<<(unsigned)(((size_t)n * 7 + 255) / 256), 256, 0, stream>>>(
      hb, P(12), P(13), P(14), P(15), xl, xr, n);
  edge_kernel<3, 14, 0><<<(unsigned)(((size_t)n * 3 + 255) / 256), 256, 0, stream>>>(
      xl, xr, indptr, csrc, P(16), P(17), P(18), P(19), P(20), P(21), hb, n);

  // layer 3: cin=42, H=3, C=12, concat, BN
  transform_kernel<42, 3, 12, 6><<<(unsigned)(((size_t)n * 6 + 255) / 256), 256, 0, stream>>>(
      hb, P(22), P(23), P(24), P(25), xl, xr, n);
  edge_kernel<3, 12, 0><<<(unsigned)(((size_t)n * 3 + 255) / 256), 256, 0, stream>>>(
      xl, xr, indptr, csrc, P(26), P(27), P(28), P(29), P(30), P(31), hb, n);

  // layer 4: cin=36, H=5, C=10, mean over heads (raw; epilogue in final_kernel)
  transform_kernel<36, 5, 10, 10><<<(unsigned)(((size_t)n * 5 + 255) / 256), 256, 0, stream>>>(
      hb, P(32), P(33), P(34), P(35), xl, xr, n);
  edge_kernel<5, 10, 2><<<(unsigned)(((size_t)n * 5 + 255) / 256), 256, 0, stream>>>(
      xl, xr, indptr, csrc, P(36), nullptr, nullptr, nullptr, nullptr, nullptr, hb, n);

  final_kernel<<<nblk, 256, 0, stream>>>(
      hb, P(37), P(38), P(39), P(40), P(41), P(42), P(43), P(44), P(45), (float*)d_out, n);
}

// Round 10
// 496.593 us; speedup vs baseline: 1.2261x; 1.0327x over previous
//
#include <hip/hip_runtime.h>

#define BN_EPS 1e-5f

typedef _Float16 half_t;
typedef _Float16 half2_t __attribute__((ext_vector_type(2)));

#define NBK_MAX 512   // max dst-buckets (256 dsts each) -> n <= 131072
#define EPB 4096      // edges staged per block in bucket scatter
#define REC 64        // xl record: 64 halves = 128 B, line-aligned
#define CAP 5120      // fixed per-bucket capacity (mean ~4352, +11 sigma)

// ---------------- bucketed CSR build (fixed-capacity buckets; no count/scan pass) ----------------

// K1: scatter (src,dst) pairs into fixed-capacity bucket staging (strided by CAP)
__global__ void __launch_bounds__(256) bucket_scatter_kernel(
    const int* __restrict__ ei, int* __restrict__ bcur, int2* __restrict__ bstage,
    int E, int etot, int nbk) {
  __shared__ int2 se[EPB];
  __shared__ int lh[NBK_MAX], lbase[NBK_MAX];
  int base = blockIdx.x * EPB;
  int cnt = min(EPB, etot - base);
  for (int i = threadIdx.x; i < nbk; i += 256) lh[i] = 0;
  __syncthreads();
  for (int i = threadIdx.x; i < cnt; i += 256) {
    int e = base + i;
    int s, d;
    if (e < E) { s = ei[e]; d = ei[E + e]; } else { s = e - E; d = s; }
    se[i] = make_int2(s, d);
    atomicAdd(&lh[d >> 8], 1);
  }
  __syncthreads();
  for (int i = threadIdx.x; i < nbk; i += 256) {
    int c = lh[i];
    lbase[i] = c ? (i * CAP + atomicAdd(&bcur[i], c)) : 0;
    lh[i] = 0;  // becomes local run cursor
  }
  __syncthreads();
  for (int i = threadIdx.x; i < cnt; i += 256) {
    int2 sd = se[i];
    int b = sd.y >> 8;
    int r = atomicAdd(&lh[b], 1);
    bstage[lbase[b] + r] = sd;
  }
}

// K2: per-bucket degree count + in-bucket scan -> start/deg, then LDS-cursor placement
__global__ void __launch_bounds__(256) csr_finalize_kernel(
    const int2* __restrict__ bstage, const int* __restrict__ bcur,
    int* __restrict__ start, int* __restrict__ deg, int* __restrict__ csrc, int n) {
  __shared__ int ld[256];
  __shared__ int wsum[4];
  int b = blockIdx.x, tid = threadIdx.x;
  int d0 = b << 8;
  int p0 = b * CAP;
  int bc = bcur[b];
  ld[tid] = 0;
  __syncthreads();
  for (int p = p0 + tid; p < p0 + bc; p += 256)
    atomicAdd(&ld[bstage[p].y - d0], 1);
  __syncthreads();
  int v = ld[tid];
  int lane = tid & 63, wid = tid >> 6;
  int incl = v;
#pragma unroll
  for (int off = 1; off < 64; off <<= 1) {
    int t = __shfl_up(incl, off, 64);
    if (lane >= off) incl += t;
  }
  if (lane == 63) wsum[wid] = incl;
  __syncthreads();
  if (tid == 0) {
    int s = 0;
#pragma unroll
    for (int w = 0; w < 4; w++) { int t = wsum[w]; wsum[w] = s; s += t; }
  }
  __syncthreads();
  incl += wsum[wid];
  int st = p0 + incl - v;
  int i = d0 + tid;
  if (i < n) { start[i] = st; deg[i] = v; }
  __syncthreads();
  ld[tid] = st;  // cursor
  __syncthreads();
  for (int p = p0 + tid; p < p0 + bc; p += 256) {
    int2 sd = bstage[p];
    int pos = atomicAdd(&ld[sd.y - d0], 1);
    csrc[pos] = sd.x;
  }
}

// ---------------- node transform ----------------
// Input IT = float (layer 1) or half_t (hb). Each thread computes JT outputs for one node.
// xl (fp16, [n][REC] 128B records, head h at half-offset h*C) = x@Wl+bl
// xr (fp16, [n][HC]) = x@Wr+br

template <int CIN, int H, int C, int JT, typename IT>
__global__ void __launch_bounds__(256) transform_kernel(
    const IT* __restrict__ x, const float* __restrict__ Wl, const float* __restrict__ Wr,
    const float* __restrict__ bl, const float* __restrict__ br, half_t* __restrict__ xl,
    half_t* __restrict__ xr, int n) {
  constexpr int HC = H * C;
  constexpr int TPN = HC / JT;  // threads per node
  __shared__ float sW[2 * CIN * HC];
  for (int i = threadIdx.x; i < CIN * HC; i += blockDim.x) {
    sW[i] = Wl[i];
    sW[CIN * HC + i] = Wr[i];
  }
  __syncthreads();
  int idx = blockIdx.x * blockDim.x + threadIdx.x;
  if (idx >= n * TPN) return;
  int node = idx / TPN;
  int j0 = (idx - node * TPN) * JT;

  float al[JT], ar[JT];
#pragma unroll
  for (int jj = 0; jj < JT; jj++) {
    al[jj] = bl[j0 + jj];
    ar[jj] = br[j0 + jj];
  }
  float xrow[CIN];
  if constexpr (sizeof(IT) == 4) {
    const float2* xp = reinterpret_cast<const float2*>((const float*)x + (size_t)node * CIN);
#pragma unroll
    for (int k2 = 0; k2 < CIN / 2; k2++) {
      float2 v = xp[k2];
      xrow[2 * k2] = v.x;
      xrow[2 * k2 + 1] = v.y;
    }
  } else {
    const half2_t* xp = reinterpret_cast<const half2_t*>((const half_t*)x + (size_t)node * CIN);
#pragma unroll
    for (int k2 = 0; k2 < CIN / 2; k2++) {
      half2_t v = xp[k2];
      xrow[2 * k2] = (float)v.x;
      xrow[2 * k2 + 1] = (float)v.y;
    }
  }
#pragma unroll
  for (int k = 0; k < CIN; k++) {
    float xs = xrow[k];
#pragma unroll
    for (int jj = 0; jj < JT; jj++) {
      al[jj] = fmaf(xs, sW[k * HC + j0 + jj], al[jj]);
      ar[jj] = fmaf(xs, sW[CIN * HC + k * HC + j0 + jj], ar[jj]);
    }
  }
#pragma unroll
  for (int jj = 0; jj < JT; jj++) {
    int j = j0 + jj;
    xl[(size_t)node * REC + j] = (half_t)al[jj];   // heads packed: offset h*C+c == j
    xr[(size_t)node * HC + j] = (half_t)ar[jj];
  }
}

// ---------------- fused edge pass ----------------
// One thread per (node, head). Each gathered node record is ONE 128B line; per-head
// slice read as C/2 dword (half2) loads. 3-deep row pipeline + 3-ahead index queue.
// MODE 0: +bias,BN  1: +bias,BN,ELU  2: raw acc/den. Output fp16.

#define IDX(K) csrc[p0 + (((K) < cnt) ? (K) : cnt - 1)]

#define ROW(B, IR)                                                                  \
  {                                                                                 \
    const uint* xp_ = reinterpret_cast<const uint*>(xlh + (size_t)(IR) * REC);      \
    _Pragma("unroll") for (int i_ = 0; i_ < C2; i_++) B[i_] = xp_[i_];              \
  }

#define COMP_ROW(B, M)                                                                      \
  {                                                                                         \
    const half2_t* hp_ = reinterpret_cast<const half2_t*>(B);                               \
    float xs_[C];                                                                           \
    _Pragma("unroll") for (int i = 0; i < C2; i++) {                                        \
      xs_[2 * i] = (float)hp_[i].x;                                                         \
      xs_[2 * i + 1] = (float)hp_[i].y;                                                     \
    }                                                                                       \
    float e_ = 0.f;                                                                         \
    _Pragma("unroll") for (int c = 0; c < C; c++) {                                         \
      float m_ = xs_[c] + xr_reg[c];                                                        \
      m_ = (m_ > 0.f) ? m_ : 0.2f * m_;                                                     \
      e_ = fmaf(att_reg[c], m_, e_);                                                        \
    }                                                                                       \
    float ex_ = ((M) < cnt) ? __expf(e_) : 0.f;                                             \
    den += ex_;                                                                             \
    _Pragma("unroll") for (int c = 0; c < C; c++) acc[c] = fmaf(ex_, xs_[c], acc[c]);       \
  }

template <int H, int C, int MODE>
__global__ void __launch_bounds__(256) edge_kernel(
    const half_t* __restrict__ xl, const half_t* __restrict__ xr,
    const int* __restrict__ start, const int* __restrict__ deg,
    const int* __restrict__ csrc, const float* __restrict__ att,
    const float* __restrict__ bias, const float* __restrict__ g,
    const float* __restrict__ be, const float* __restrict__ rm,
    const float* __restrict__ rv, half_t* __restrict__ out, int n) {
  constexpr int HC = H * C;
  constexpr int C2 = C / 2;
  int t = blockIdx.x * blockDim.x + threadIdx.x;
  if (t >= n * H) return;
  int node = t / H;
  int h = t - node * H;

  float xr_reg[C], att_reg[C];
  const half2_t* xrp = reinterpret_cast<const half2_t*>(xr + (size_t)node * HC + h * C);
#pragma unroll
  for (int i = 0; i < C2; i++) {
    half2_t v = xrp[i];
    xr_reg[2 * i] = (float)v.x;
    xr_reg[2 * i + 1] = (float)v.y;
  }
#pragma unroll
  for (int c = 0; c < C; c++) att_reg[c] = att[h * C + c];

  float acc[C];
#pragma unroll
  for (int c = 0; c < C; c++) acc[c] = 0.f;
  float den = 0.f;

  int p0 = start[node];
  int cnt = deg[node];
  const half_t* xlh = xl + h * C;  // head slice within the 128B record

  uint B0[C2], B1[C2], B2[C2];
  int i0, i1, i2;
  i0 = IDX(0); i1 = IDX(1); i2 = IDX(2);
  ROW(B0, i0) ROW(B1, i1) ROW(B2, i2)
  i0 = IDX(3); i1 = IDX(4); i2 = IDX(5);
  int cnt3 = ((cnt + 2) / 3) * 3;
  for (int m = 0; m < cnt3; m += 3) {
    COMP_ROW(B0, m)     ROW(B0, i0) i0 = IDX(m + 6);
    COMP_ROW(B1, m + 1) ROW(B1, i1) i1 = IDX(m + 7);
    COMP_ROW(B2, m + 2) ROW(B2, i2) i2 = IDX(m + 8);
  }

  float inv = 1.f / den;
  uint* orow = reinterpret_cast<uint*>(out + (size_t)node * HC + h * C);
#pragma unroll
  for (int c2 = 0; c2 < C2; c2++) {
    half2_t ov;
#pragma unroll
    for (int q = 0; q < 2; q++) {
      int c = 2 * c2 + q;
      float val = acc[c] * inv;
      if constexpr (MODE != 2) {
        int j = h * C + c;
        val += bias[j];
        float sc = g[j] * rsqrtf(rv[j] + BN_EPS);
        val = fmaf(sc, val - rm[j], be[j]);
        if constexpr (MODE == 1) val = (val > 0.f) ? val : expm1f(val);
      }
      if (q) ov.y = (half_t)val; else ov.x = (half_t)val;
    }
    orow[c2] = *reinterpret_cast<uint*>(&ov);
  }
}

// ---------------- layer-4 tail: mean over heads + bias + BN + mu/logvar heads ----------------

__global__ void final_kernel(const half_t* __restrict__ r4, const float* __restrict__ b4,
                             const float* __restrict__ g4, const float* __restrict__ be4,
                             const float* __restrict__ rm4, const float* __restrict__ rv4,
                             const float* __restrict__ Wmu, const float* __restrict__ bmu,
                             const float* __restrict__ Wlv, const float* __restrict__ blv,
                             float* __restrict__ out, int n) {
  int node = blockIdx.x * blockDim.x + threadIdx.x;
  if (node >= n) return;
  float hsum[10];
#pragma unroll
  for (int c = 0; c < 10; c++) hsum[c] = 0.f;
  const half2_t* r = reinterpret_cast<const half2_t*>(r4 + (size_t)node * 50);
  float rv_[50];
#pragma unroll
  for (int i = 0; i < 25; i++) {
    half2_t v = r[i];
    rv_[2 * i] = (float)v.x;
    rv_[2 * i + 1] = (float)v.y;
  }
#pragma unroll
  for (int h = 0; h < 5; h++)
#pragma unroll
    for (int c = 0; c < 10; c++) hsum[c] += rv_[h * 10 + c];
  float hv[10];
#pragma unroll
  for (int c = 0; c < 10; c++) {
    float v = hsum[c] * 0.2f + b4[c];
    float sc = g4[c] * rsqrtf(rv4[c] + BN_EPS);
    hv[c] = fmaf(sc, v - rm4[c], be4[c]);
  }
#pragma unroll
  for (int j = 0; j < 10; j++) {
    float mu = bmu[j], lv = blv[j];
#pragma unroll
    for (int c = 0; c < 10; c++) {
      mu = fmaf(hv[c], Wmu[c * 10 + j], mu);
      lv = fmaf(hv[c], Wlv[c * 10 + j], lv);
    }
    out[(size_t)node * 10 + j] = mu;
    out[(size_t)n * 10 + (size_t)node * 10 + j] = lv;
  }
}

// ---------------- launch ----------------

extern "C" void kernel_launch(void* const* d_in, const int* in_sizes, int n_in,
                              void* d_out, int out_size, void* d_ws, size_t ws_size,
                              hipStream_t stream) {
  const float* x = (const float*)d_in[0];
  const int* ei = (const int*)d_in[1];
  const int n = in_sizes[0] / 22;
  const int E = in_sizes[1] / 2;
  const int etot = E + n;
  const int nbk = (n + 255) >> 8;  // 256-dst buckets

  auto P = [&](int i) { return (const float*)d_in[i]; };

  char* ws = (char*)d_ws;
  size_t off = 0;
  auto alloc = [&](size_t bytes) -> void* {
    void* p = ws + off;
    off += (bytes + 255) & ~(size_t)255;
    return p;
  };
  half_t* xl = (half_t*)alloc((size_t)n * REC * 2);  // 12.8 MB, 128B-aligned records
  half_t* xr = (half_t*)alloc((size_t)n * 54 * 2);   // 10.8 MB
  half_t* hb = (half_t*)alloc((size_t)n * 54 * 2);   // 10.8 MB
  int* start = (int*)alloc((size_t)n * 4);
  int* deg = (int*)alloc((size_t)n * 4);
  int* csrc = (int*)alloc((size_t)nbk * CAP * 4);    // strided buckets (gaps ok)
  int* bcur = (int*)alloc((size_t)nbk * 4);
  // bstage aliases xl+xr region (16 MB; only live before transforms run)
  int2* bstage = (int2*)xl;

  unsigned bb = (unsigned)((etot + EPB - 1) / EPB);
  unsigned nblk = (unsigned)((n + 255) / 256);

  hipMemsetAsync(bcur, 0, (size_t)nbk * 4, stream);
  bucket_scatter_kernel<<<bb, 256, 0, stream>>>(ei, bcur, bstage, E, etot, nbk);
  csr_finalize_kernel<<<(unsigned)nbk, 256, 0, stream>>>(bstage, bcur, start, deg, csrc, n);

  // layer 1: cin=22, H=3, C=18, concat, BN+ELU
  transform_kernel<22, 3, 18, 6, float><<<(unsigned)(((size_t)n * 9 + 255) / 256), 256, 0, stream>>>(
      x, P(2), P(3), P(4), P(5), xl, xr, n);
  edge_kernel<3, 18, 1><<<(unsigned)(((size_t)n * 3 + 255) / 256), 256, 0, stream>>>(
      xl, xr, start, deg, csrc, P(6), P(7), P(8), P(9), P(10), P(11), hb, n);

  // layer 2: cin=54, H=3, C=14, concat, BN
  transform_kernel<54, 3, 14, 6, half_t><<<(unsigned)(((size_t)n * 7 + 255) / 256), 256, 0, stream>>>(
      hb, P(12), P(13), P(14), P(15), xl, xr, n);
  edge_kernel<3, 14, 0><<<(unsigned)(((size_t)n * 3 + 255) / 256), 256, 0, stream>>>(
      xl, xr, start, deg, csrc, P(16), P(17), P(18), P(19), P(20), P(21), hb, n);

  // layer 3: cin=42, H=3, C=12, concat, BN
  transform_kernel<42, 3, 12, 6, half_t><<<(unsigned)(((size_t)n * 6 + 255) / 256), 256, 0, stream>>>(
      hb, P(22), P(23), P(24), P(25), xl, xr, n);
  edge_kernel<3, 12, 0><<<(unsigned)(((size_t)n * 3 + 255) / 256), 256, 0, stream>>>(
      xl, xr, start, deg, csrc, P(26), P(27), P(28), P(29), P(30), P(31), hb, n);

  // layer 4: cin=36, H=5, C=10, mean over heads (raw; epilogue in final_kernel)
  transform_kernel<36, 5, 10, 10, half_t><<<(unsigned)(((size_t)n * 5 + 255) / 256), 256, 0, stream>>>(
      hb, P(32), P(33), P(34), P(35), xl, xr, n);
  edge_kernel<5, 10, 2><<<(unsigned)(((size_t)n * 5 + 255) / 256), 256, 0, stream>>>(
      xl, xr, start, deg, csrc, P(36), nullptr, nullptr, nullptr, nullptr, nullptr, hb, n);

  final_kernel<<<nblk, 256, 0, stream>>>(
      hb, P(37), P(38), P(39), P(40), P(41), P(42), P(43), P(44), P(45), (float*)d_out, n);
}

// Round 11
// 478.752 us; speedup vs baseline: 1.2718x; 1.0373x over previous
//
#include <hip/hip_runtime.h>

#define BN_EPS 1e-5f

typedef _Float16 half_t;
typedef _Float16 half2_t __attribute__((ext_vector_type(2)));

#define NBK_MAX 512   // max dst-buckets (256 dsts each) -> n <= 131072
#define EPB 8192      // edges per block in bucket scatter
#define REC 64        // xl record: 64 halves = 128 B, line-aligned
#define CAP 5120      // fixed per-bucket capacity (mean ~4350, +11 sigma)

#if __has_builtin(__builtin_amdgcn_fdot2)
#define DOT2(a, b, c) __builtin_amdgcn_fdot2((a), (b), (c), false)
#else
#define DOT2(a, b, c) fmaf((float)(a).x, (float)(b).x, fmaf((float)(a).y, (float)(b).y, (c)))
#endif

// ---------------- bucketed CSR build (fixed-capacity buckets, packed entries) ----------------

// K1: two-pass over this block's ei slice (L2-hot): count per bucket, reserve, place.
// bstage entry = (src << 8) | (dst & 255); bucket implied by slot (strided by CAP).
__global__ void __launch_bounds__(256) bucket_scatter_kernel(
    const int* __restrict__ ei, int* __restrict__ bcur, unsigned* __restrict__ bstage,
    int E, int etot, int nbk) {
  __shared__ int lh[NBK_MAX], lbase[NBK_MAX];
  int base = blockIdx.x * EPB;
  int cnt = min(EPB, etot - base);
  for (int i = threadIdx.x; i < nbk; i += 256) lh[i] = 0;
  __syncthreads();
  for (int i = threadIdx.x; i < cnt; i += 256) {
    int e = base + i;
    int d = (e < E) ? ei[E + e] : (e - E);
    atomicAdd(&lh[d >> 8], 1);
  }
  __syncthreads();
  for (int i = threadIdx.x; i < nbk; i += 256) {
    int c = lh[i];
    lbase[i] = c ? (i * CAP + atomicAdd(&bcur[i], c)) : 0;
    lh[i] = 0;  // becomes local run cursor
  }
  __syncthreads();
  for (int i = threadIdx.x; i < cnt; i += 256) {
    int e = base + i;
    int s, d;
    if (e < E) { s = ei[e]; d = ei[E + e]; } else { s = e - E; d = s; }
    int b = d >> 8;
    int r = atomicAdd(&lh[b], 1);
    bstage[lbase[b] + r] = ((unsigned)s << 8) | (unsigned)(d & 255);
  }
}

// K2: per-bucket degree count + in-bucket scan -> start/deg, then LDS-cursor placement
__global__ void __launch_bounds__(256) csr_finalize_kernel(
    const unsigned* __restrict__ bstage, const int* __restrict__ bcur,
    int* __restrict__ start, int* __restrict__ deg, int* __restrict__ csrc, int n) {
  __shared__ int ld[256];
  __shared__ int wsum[4];
  int b = blockIdx.x, tid = threadIdx.x;
  int d0 = b << 8;
  int p0 = b * CAP;
  int bc = bcur[b];
  ld[tid] = 0;
  __syncthreads();
  for (int p = p0 + tid; p < p0 + bc; p += 256)
    atomicAdd(&ld[bstage[p] & 255u], 1);
  __syncthreads();
  int v = ld[tid];
  int lane = tid & 63, wid = tid >> 6;
  int incl = v;
#pragma unroll
  for (int off = 1; off < 64; off <<= 1) {
    int t = __shfl_up(incl, off, 64);
    if (lane >= off) incl += t;
  }
  if (lane == 63) wsum[wid] = incl;
  __syncthreads();
  if (tid == 0) {
    int s = 0;
#pragma unroll
    for (int w = 0; w < 4; w++) { int t = wsum[w]; wsum[w] = s; s += t; }
  }
  __syncthreads();
  incl += wsum[wid];
  int st = p0 + incl - v;
  int i = d0 + tid;
  if (i < n) { start[i] = st; deg[i] = v; }
  __syncthreads();
  ld[tid] = st;  // cursor
  __syncthreads();
  for (int p = p0 + tid; p < p0 + bc; p += 256) {
    unsigned sd = bstage[p];
    int pos = atomicAdd(&ld[sd & 255u], 1);
    csrc[pos] = (int)(sd >> 8);
  }
}

// ---------------- node transform ----------------
// Input IT = float (layer 1) or half_t (hb). Each thread computes JT outputs for one node.
// xl (fp16, [n][REC] 128B records, head h at half-offset h*C) = x@Wl+bl
// xr (fp16, [n][HC]) = x@Wr+br

template <int CIN, int H, int C, int JT, typename IT>
__global__ void __launch_bounds__(256) transform_kernel(
    const IT* __restrict__ x, const float* __restrict__ Wl, const float* __restrict__ Wr,
    const float* __restrict__ bl, const float* __restrict__ br, half_t* __restrict__ xl,
    half_t* __restrict__ xr, int n) {
  constexpr int HC = H * C;
  constexpr int TPN = HC / JT;  // threads per node
  __shared__ float sW[2 * CIN * HC];
  for (int i = threadIdx.x; i < CIN * HC; i += blockDim.x) {
    sW[i] = Wl[i];
    sW[CIN * HC + i] = Wr[i];
  }
  __syncthreads();
  int idx = blockIdx.x * blockDim.x + threadIdx.x;
  if (idx >= n * TPN) return;
  int node = idx / TPN;
  int j0 = (idx - node * TPN) * JT;

  float al[JT], ar[JT];
#pragma unroll
  for (int jj = 0; jj < JT; jj++) {
    al[jj] = bl[j0 + jj];
    ar[jj] = br[j0 + jj];
  }
  float xrow[CIN];
  if constexpr (sizeof(IT) == 4) {
    const float2* xp = reinterpret_cast<const float2*>((const float*)x + (size_t)node * CIN);
#pragma unroll
    for (int k2 = 0; k2 < CIN / 2; k2++) {
      float2 v = xp[k2];
      xrow[2 * k2] = v.x;
      xrow[2 * k2 + 1] = v.y;
    }
  } else {
    const half2_t* xp = reinterpret_cast<const half2_t*>((const half_t*)x + (size_t)node * CIN);
#pragma unroll
    for (int k2 = 0; k2 < CIN / 2; k2++) {
      half2_t v = xp[k2];
      xrow[2 * k2] = (float)v.x;
      xrow[2 * k2 + 1] = (float)v.y;
    }
  }
#pragma unroll
  for (int k = 0; k < CIN; k++) {
    float xs = xrow[k];
#pragma unroll
    for (int jj = 0; jj < JT; jj++) {
      al[jj] = fmaf(xs, sW[k * HC + j0 + jj], al[jj]);
      ar[jj] = fmaf(xs, sW[CIN * HC + k * HC + j0 + jj], ar[jj]);
    }
  }
#pragma unroll
  for (int jj = 0; jj < JT; jj++) {
    int j = j0 + jj;
    xl[(size_t)node * REC + j] = (half_t)al[jj];   // heads packed: offset h*C+c == j
    xr[(size_t)node * HC + j] = (half_t)ar[jj];
  }
}

// ---------------- fused edge pass ----------------
// One thread per (node, head); gathered record = ONE 128B line. Packed-half2 math:
// m/leaky via v_pk ops, score via v_dot2_f32_f16 (f32 accum), acc via v_pk_fma_f16.
// den stays f32. 3-deep row pipeline + 3-ahead index queue.
// MODE 0: +bias,BN  1: +bias,BN,ELU  2: raw acc/den. Output fp16.

#define IDX(K) csrc[p0 + (((K) < cnt) ? (K) : cnt - 1)]

#define ROW(B, IR)                                                                  \
  {                                                                                 \
    const uint* xp_ = reinterpret_cast<const uint*>(xlh + (size_t)(IR) * REC);      \
    _Pragma("unroll") for (int i_ = 0; i_ < C2; i_++) B[i_] = xp_[i_];              \
  }

#define COMP_ROW(B, M)                                                              \
  {                                                                                 \
    const half2_t* hp_ = reinterpret_cast<const half2_t*>(B);                       \
    float e_ = 0.f;                                                                 \
    _Pragma("unroll") for (int i = 0; i < C2; i++) {                                \
      half2_t m_ = hp_[i] + xr_h[i];                                                \
      half2_t mp_ = __builtin_elementwise_max(m_, h2z);                             \
      half2_t mn_ = __builtin_elementwise_min(m_, h2z);                             \
      m_ = mp_ + mn_ * h2lk;                                                        \
      e_ = DOT2(att_h[i], m_, e_);                                                  \
    }                                                                               \
    float ex_ = ((M) < cnt) ? __expf(e_) : 0.f;                                     \
    den += ex_;                                                                     \
    half_t exs_ = (half_t)ex_;                                                      \
    half2_t exv_ = {exs_, exs_};                                                    \
    _Pragma("unroll") for (int i = 0; i < C2; i++) acc[i] += exv_ * hp_[i];         \
  }

template <int H, int C, int MODE>
__global__ void __launch_bounds__(256) edge_kernel(
    const half_t* __restrict__ xl, const half_t* __restrict__ xr,
    const int* __restrict__ start, const int* __restrict__ deg,
    const int* __restrict__ csrc, const float* __restrict__ att,
    const float* __restrict__ bias, const float* __restrict__ g,
    const float* __restrict__ be, const float* __restrict__ rm,
    const float* __restrict__ rv, half_t* __restrict__ out, int n) {
  constexpr int HC = H * C;
  constexpr int C2 = C / 2;
  int t = blockIdx.x * blockDim.x + threadIdx.x;
  if (t >= n * H) return;
  int node = t / H;
  int h = t - node * H;

  const half2_t h2z = {(half_t)0.f, (half_t)0.f};
  const half2_t h2lk = {(half_t)0.2f, (half_t)0.2f};

  half2_t xr_h[C2], att_h[C2], acc[C2];
  const half2_t* xrp = reinterpret_cast<const half2_t*>(xr + (size_t)node * HC + h * C);
#pragma unroll
  for (int i = 0; i < C2; i++) {
    xr_h[i] = xrp[i];
    att_h[i] = half2_t{(half_t)att[h * C + 2 * i], (half_t)att[h * C + 2 * i + 1]};
    acc[i] = h2z;
  }
  float den = 0.f;

  int p0 = start[node];
  int cnt = deg[node];
  const half_t* xlh = xl + h * C;  // head slice within the 128B record

  uint B0[C2], B1[C2], B2[C2];
  int i0, i1, i2;
  i0 = IDX(0); i1 = IDX(1); i2 = IDX(2);
  ROW(B0, i0) ROW(B1, i1) ROW(B2, i2)
  i0 = IDX(3); i1 = IDX(4); i2 = IDX(5);
  int cnt3 = ((cnt + 2) / 3) * 3;
  for (int m = 0; m < cnt3; m += 3) {
    COMP_ROW(B0, m)     ROW(B0, i0) i0 = IDX(m + 6);
    COMP_ROW(B1, m + 1) ROW(B1, i1) i1 = IDX(m + 7);
    COMP_ROW(B2, m + 2) ROW(B2, i2) i2 = IDX(m + 8);
  }

  float inv = 1.f / den;
  uint* orow = reinterpret_cast<uint*>(out + (size_t)node * HC + h * C);
#pragma unroll
  for (int c2 = 0; c2 < C2; c2++) {
    half2_t ov;
#pragma unroll
    for (int q = 0; q < 2; q++) {
      float a = q ? (float)acc[c2].y : (float)acc[c2].x;
      float val = a * inv;
      if constexpr (MODE != 2) {
        int j = h * C + 2 * c2 + q;
        val += bias[j];
        float sc = g[j] * rsqrtf(rv[j] + BN_EPS);
        val = fmaf(sc, val - rm[j], be[j]);
        if constexpr (MODE == 1) val = (val > 0.f) ? val : expm1f(val);
      }
      if (q) ov.y = (half_t)val; else ov.x = (half_t)val;
    }
    orow[c2] = *reinterpret_cast<uint*>(&ov);
  }
}

// ---------------- layer-4 tail: mean over heads + bias + BN + mu/logvar heads ----------------

__global__ void final_kernel(const half_t* __restrict__ r4, const float* __restrict__ b4,
                             const float* __restrict__ g4, const float* __restrict__ be4,
                             const float* __restrict__ rm4, const float* __restrict__ rv4,
                             const float* __restrict__ Wmu, const float* __restrict__ bmu,
                             const float* __restrict__ Wlv, const float* __restrict__ blv,
                             float* __restrict__ out, int n) {
  int node = blockIdx.x * blockDim.x + threadIdx.x;
  if (node >= n) return;
  float hsum[10];
#pragma unroll
  for (int c = 0; c < 10; c++) hsum[c] = 0.f;
  const half2_t* r = reinterpret_cast<const half2_t*>(r4 + (size_t)node * 50);
  float rv_[50];
#pragma unroll
  for (int i = 0; i < 25; i++) {
    half2_t v = r[i];
    rv_[2 * i] = (float)v.x;
    rv_[2 * i + 1] = (float)v.y;
  }
#pragma unroll
  for (int h = 0; h < 5; h++)
#pragma unroll
    for (int c = 0; c < 10; c++) hsum[c] += rv_[h * 10 + c];
  float hv[10];
#pragma unroll
  for (int c = 0; c < 10; c++) {
    float v = hsum[c] * 0.2f + b4[c];
    float sc = g4[c] * rsqrtf(rv4[c] + BN_EPS);
    hv[c] = fmaf(sc, v - rm4[c], be4[c]);
  }
#pragma unroll
  for (int j = 0; j < 10; j++) {
    float mu = bmu[j], lv = blv[j];
#pragma unroll
    for (int c = 0; c < 10; c++) {
      mu = fmaf(hv[c], Wmu[c * 10 + j], mu);
      lv = fmaf(hv[c], Wlv[c * 10 + j], lv);
    }
    out[(size_t)node * 10 + j] = mu;
    out[(size_t)n * 10 + (size_t)node * 10 + j] = lv;
  }
}

// ---------------- launch ----------------

extern "C" void kernel_launch(void* const* d_in, const int* in_sizes, int n_in,
                              void* d_out, int out_size, void* d_ws, size_t ws_size,
                              hipStream_t stream) {
  const float* x = (const float*)d_in[0];
  const int* ei = (const int*)d_in[1];
  const int n = in_sizes[0] / 22;
  const int E = in_sizes[1] / 2;
  const int etot = E + n;
  const int nbk = (n + 255) >> 8;  // 256-dst buckets

  auto P = [&](int i) { return (const float*)d_in[i]; };

  char* ws = (char*)d_ws;
  size_t off = 0;
  auto alloc = [&](size_t bytes) -> void* {
    void* p = ws + off;
    off += (bytes + 255) & ~(size_t)255;
    return p;
  };
  half_t* xl = (half_t*)alloc((size_t)n * REC * 2);  // 12.8 MB, 128B-aligned records
  half_t* xr = (half_t*)alloc((size_t)n * 54 * 2);   // 10.8 MB
  half_t* hb = (half_t*)alloc((size_t)n * 54 * 2);   // 10.8 MB
  int* start = (int*)alloc((size_t)n * 4);
  int* deg = (int*)alloc((size_t)n * 4);
  int* csrc = (int*)alloc((size_t)nbk * CAP * 4);    // strided buckets (gaps ok)
  int* bcur = (int*)alloc((size_t)nbk * 4);
  // bstage (uint, 8 MB) aliases xl region (only live before transforms run)
  unsigned* bstage = (unsigned*)xl;

  unsigned bb = (unsigned)((etot + EPB - 1) / EPB);
  unsigned nblk = (unsigned)((n + 255) / 256);

  hipMemsetAsync(bcur, 0, (size_t)nbk * 4, stream);
  bucket_scatter_kernel<<<bb, 256, 0, stream>>>(ei, bcur, bstage, E, etot, nbk);
  csr_finalize_kernel<<<(unsigned)nbk, 256, 0, stream>>>(bstage, bcur, start, deg, csrc, n);

  // layer 1: cin=22, H=3, C=18, concat, BN+ELU
  transform_kernel<22, 3, 18, 6, float><<<(unsigned)(((size_t)n * 9 + 255) / 256), 256, 0, stream>>>(
      x, P(2), P(3), P(4), P(5), xl, xr, n);
  edge_kernel<3, 18, 1><<<(unsigned)(((size_t)n * 3 + 255) / 256), 256, 0, stream>>>(
      xl, xr, start, deg, csrc, P(6), P(7), P(8), P(9), P(10), P(11), hb, n);

  // layer 2: cin=54, H=3, C=14, concat, BN
  transform_kernel<54, 3, 14, 6, half_t><<<(unsigned)(((size_t)n * 7 + 255) / 256), 256, 0, stream>>>(
      hb, P(12), P(13), P(14), P(15), xl, xr, n);
  edge_kernel<3, 14, 0><<<(unsigned)(((size_t)n * 3 + 255) / 256), 256, 0, stream>>>(
      xl, xr, start, deg, csrc, P(16), P(17), P(18), P(19), P(20), P(21), hb, n);

  // layer 3: cin=42, H=3, C=12, concat, BN
  transform_kernel<42, 3, 12, 6, half_t><<<(unsigned)(((size_t)n * 6 + 255) / 256), 256, 0, stream>>>(
      hb, P(22), P(23), P(24), P(25), xl, xr, n);
  edge_kernel<3, 12, 0><<<(unsigned)(((size_t)n * 3 + 255) / 256), 256, 0, stream>>>(
      xl, xr, start, deg, csrc, P(26), P(27), P(28), P(29), P(30), P(31), hb, n);

  // layer 4: cin=36, H=5, C=10, mean over heads (raw; epilogue in final_kernel)
  transform_kernel<36, 5, 10, 10, half_t><<<(unsigned)(((size_t)n * 5 + 255) / 256), 256, 0, stream>>>(
      hb, P(32), P(33), P(34), P(35), xl, xr, n);
  edge_kernel<5, 10, 2><<<(unsigned)(((size_t)n * 5 + 255) / 256), 256, 0, stream>>>(
      xl, xr, start, deg, csrc, P(36), nullptr, nullptr, nullptr, nullptr, nullptr, hb, n);

  final_kernel<<<nblk, 256, 0, stream>>>(
      hb, P(37), P(38), P(39), P(40), P(41), P(42), P(43), P(44), P(45), (float*)d_out, n);
}